// Round 8
// baseline (220.669 us; speedup 1.0000x reference)
//
#include <hip/hip_runtime.h>
#include <math.h>

#define N_LAYERS 8
#define TAB 48
#define TABSZ (TAB * TAB)
#define LOG2E2 2.8853900817779268f   // 2*log2(e)
#define NLOG2E 1.4426950408889634f   // log2(e)
#define UCLAMP 24.0f                  // exp2 clamp
#define BLK 512

// Heterogeneous split: grid = 2048 blocks = 32 super-groups of 64.
// Role selector uses bits [3:5] of blockIdx: under round-robin XCD dispatch
// (blockIdx%8 == XCD id, constant per XCD), these bits cycle WITHIN each
// XCD's block stream -> every CU co-hosts ~3 table-blocks + 1 direct-block.
// j = (b>>3)&7: j<6 -> table role (1536 blocks, 75% of pairs, r1 body);
//               j>=6 -> direct role (512 blocks, 25% of pairs, r7 body).
#define TTH (1536 * BLK)             // table-role thread count (786432)
#define DTH (512 * BLK)              // direct-role thread count (262144)
#define DBASE (4 * TTH)              // first float4-group of direct role

#if __has_builtin(__builtin_amdgcn_exp2f)
__device__ __forceinline__ float exp2_fast(float x) { return __builtin_amdgcn_exp2f(x); }
#else
__device__ __forceinline__ float exp2_fast(float x) { return __expf(0.6931471805599453f * x); }
#endif

// d_ws float layout:
//  [0..13]    table meta (log2-domain input layer W~,b~; C,D; lo,h)
//  [100..192] direct-eval per-layer consts {W~(4),b~(2),-2s(2),s+t(2)} x9 + {Wf0,Wf1,bf}
//  fp+256 ..  gt4 : packed CR rows, TABSZ float4 (36 KB)

__global__ __launch_bounds__(64) void setup48(
    const float* __restrict__ W0, const float* __restrict__ b0,
    const float* __restrict__ s0, const float* __restrict__ t0,
    const float* __restrict__ Ws, const float* __restrict__ bs,
    const float* __restrict__ ss, const float* __restrict__ ts,
    const float* __restrict__ Wf, const float* __restrict__ bf,
    float* __restrict__ fp, float4* __restrict__ gt4) {
    __shared__ float fs[16];
    __shared__ float row[TAB];
    int iy = blockIdx.x;      // table row
    int tx = threadIdx.x;

    if (tx == 0) {
        fs[0] = LOG2E2 * W0[0]; fs[1] = LOG2E2 * W0[1];
        fs[2] = LOG2E2 * W0[2]; fs[3] = LOG2E2 * W0[3];
        fs[4] = LOG2E2 * b0[0]; fs[5] = LOG2E2 * b0[1];
        for (int c = 0; c < 2; ++c) {
            float s = s0[c], t = t0[c];
            float span = fmaxf(2.2f * s, 1e-5f);   // 10% pad each side
            float h  = span / (float)(TAB - 1);
            float lo = t - 0.5f * span;
            float ih = (float)(TAB - 1) / span;
            fs[6 + c]  = (s + 0.5f * span) * ih;   // C
            fs[8 + c]  = 2.0f * s * ih;            // D
            fs[10 + c] = lo;
            fs[12 + c] = h;
        }
        if (iy == 0) {
            for (int i = 0; i < 14; ++i) fp[i] = fs[i];
            // direct-eval consts (r7 layout, shifted to +100)
            float* q = fp + 100;
            q[0] = LOG2E2 * W0[0]; q[1] = LOG2E2 * W0[1];
            q[2] = LOG2E2 * W0[2]; q[3] = LOG2E2 * W0[3];
            q[4] = LOG2E2 * b0[0]; q[5] = LOG2E2 * b0[1];
            q[6] = -2.0f * s0[0];  q[7] = -2.0f * s0[1];
            q[8] = s0[0] + t0[0];  q[9] = s0[1] + t0[1];
            for (int l = 0; l < N_LAYERS; ++l) {
                float* p = q + 10 * (l + 1);
                p[0] = LOG2E2 * Ws[4 * l + 0]; p[1] = LOG2E2 * Ws[4 * l + 1];
                p[2] = LOG2E2 * Ws[4 * l + 2]; p[3] = LOG2E2 * Ws[4 * l + 3];
                p[4] = LOG2E2 * bs[2 * l + 0]; p[5] = LOG2E2 * bs[2 * l + 1];
                p[6] = -2.0f * ss[2 * l + 0];  p[7] = -2.0f * ss[2 * l + 1];
                p[8] = ss[2 * l + 0] + ts[2 * l + 0];
                p[9] = ss[2 * l + 1] + ts[2 * l + 1];
            }
            q[90] = Wf[0]; q[91] = Wf[1]; q[92] = bf[0];
        }
    }
    __syncthreads();

    if (tx < TAB) {
        float z0 = fs[10] + (float)tx * fs[12];
        float z1 = fs[11] + (float)iy * fs[13];
        for (int l = 0; l < N_LAYERS; ++l) {
            float u0 = fmaf(z0, Ws[4 * l + 0], fmaf(z1, Ws[4 * l + 1], bs[2 * l + 0]));
            float u1 = fmaf(z0, Ws[4 * l + 2], fmaf(z1, Ws[4 * l + 3], bs[2 * l + 1]));
            z0 = fmaf(tanhf(u0), ss[2 * l + 0], ts[2 * l + 0]);
            z1 = fmaf(tanhf(u1), ss[2 * l + 1], ts[2 * l + 1]);
        }
        row[tx] = fmaf(z0, Wf[0], fmaf(z1, Wf[1], bf[0]));
    }
    __syncthreads();

    if (tx < TAB) {
        int c0 = max(tx - 1, 0);
        int c2 = min(tx + 1, TAB - 1);
        int c3 = min(tx + 2, TAB - 1);
        gt4[iy * TAB + tx] = make_float4(row[c0], row[tx], row[c2], row[c3]);
    }
}

// ---------- table path (verbatim r1 math) ----------
__device__ __forceinline__ void cr_w(float f, float w[4]) {
    w[0] = f * fmaf(f, fmaf(f, -0.5f, 1.0f), -0.5f);
    w[1] = fmaf(f * f, fmaf(f, 1.5f, -2.5f), 1.0f);
    w[2] = f * fmaf(f, fmaf(f, -1.5f, 2.0f), 0.5f);
    w[3] = f * f * fmaf(f, 0.5f, -0.5f);
}

__device__ __forceinline__ float interp_two(const float4* __restrict__ tab4,
                                            float ax0, float ax1, float ay0, float ay1) {
    int ixa = min(max((int)ax0, 1), TAB - 3);
    int iya = min(max((int)ax1, 1), TAB - 3);
    int ixb = min(max((int)ay0, 1), TAB - 3);
    int iyb = min(max((int)ay1, 1), TAB - 3);
    float fxa = ax0 - (float)ixa, fya = ax1 - (float)iya;
    float fxb = ay0 - (float)ixb, fyb = ay1 - (float)iyb;

    const float4* pa = tab4 + (iya - 1) * TAB + ixa;
    const float4* pb = tab4 + (iyb - 1) * TAB + ixb;
    float4 a0 = pa[0], a1 = pa[TAB], a2 = pa[2 * TAB], a3 = pa[3 * TAB];
    float4 b0 = pb[0], b1 = pb[TAB], b2 = pb[2 * TAB], b3 = pb[3 * TAB];

    float wxa[4], wya[4], wxb[4], wyb[4];
    cr_w(fxa, wxa); cr_w(fya, wya);
    cr_w(fxb, wxb); cr_w(fyb, wyb);

    float ra0 = fmaf(a0.w, wxa[3], fmaf(a0.z, wxa[2], fmaf(a0.y, wxa[1], a0.x * wxa[0])));
    float ra1 = fmaf(a1.w, wxa[3], fmaf(a1.z, wxa[2], fmaf(a1.y, wxa[1], a1.x * wxa[0])));
    float ra2 = fmaf(a2.w, wxa[3], fmaf(a2.z, wxa[2], fmaf(a2.y, wxa[1], a2.x * wxa[0])));
    float ra3 = fmaf(a3.w, wxa[3], fmaf(a3.z, wxa[2], fmaf(a3.y, wxa[1], a3.x * wxa[0])));
    float gx  = fmaf(ra3, wya[3], fmaf(ra2, wya[2], fmaf(ra1, wya[1], ra0 * wya[0])));

    float rb0 = fmaf(b0.w, wxb[3], fmaf(b0.z, wxb[2], fmaf(b0.y, wxb[1], b0.x * wxb[0])));
    float rb1 = fmaf(b1.w, wxb[3], fmaf(b1.z, wxb[2], fmaf(b1.y, wxb[1], b1.x * wxb[0])));
    float rb2 = fmaf(b2.w, wxb[3], fmaf(b2.z, wxb[2], fmaf(b2.y, wxb[1], b2.x * wxb[0])));
    float rb3 = fmaf(b3.w, wxb[3], fmaf(b3.z, wxb[2], fmaf(b3.y, wxb[1], b3.x * wxb[0])));
    float gy  = fmaf(rb3, wyb[3], fmaf(rb2, wyb[2], fmaf(rb1, wyb[1], rb0 * wyb[0])));

    return gx * gy;
}

__device__ __forceinline__ float pair_val(const float4* __restrict__ tab4,
                                          float px0, float px1, float py0, float py1,
                                          float C0, float C1, float D0, float D1) {
    float d0 = exp2_fast(fminf(px0, UCLAMP)) + 1.0f;
    float d1 = exp2_fast(fminf(px1, UCLAMP)) + 1.0f;
    float d2 = exp2_fast(fminf(py0, UCLAMP)) + 1.0f;
    float d3 = exp2_fast(fminf(py1, UCLAMP)) + 1.0f;
    float p2 = d0 * d1, p3 = p2 * d2, p4 = p3 * d3;
    float R = __builtin_amdgcn_rcpf(p4);
    float i3 = R * p3;  R *= d3;
    float i2 = R * p2;  R *= d2;
    float i1 = R * d0;
    float i0 = R * d1;
    float ux0 = fmaf(-D0, i0, C0), ux1 = fmaf(-D1, i1, C1);
    float uy0 = fmaf(-D0, i2, C0), uy1 = fmaf(-D1, i3, C1);
    return interp_two(tab4, ux0, ux1, uy0, uy1);
}

// ---------- direct path (verbatim r7 math) ----------
__device__ __forceinline__ float net_eval(const float* __restrict__ fq,
                                          float z0, float z1) {
#pragma unroll
    for (int l = 0; l < N_LAYERS + 1; ++l) {
        const float* q = fq + 10 * l;
        float u0 = fmaf(z0, q[0], fmaf(z1, q[1], q[4]));
        float u1 = fmaf(z0, q[2], fmaf(z1, q[3], q[5]));
        float d0 = exp2_fast(fminf(u0, UCLAMP)) + 1.0f;
        float d1 = exp2_fast(fminf(u1, UCLAMP)) + 1.0f;
        float R  = __builtin_amdgcn_rcpf(d0 * d1);
        float i0 = R * d1;
        float i1 = R * d0;
        z0 = fmaf(q[6], i0, q[8]);
        z1 = fmaf(q[7], i1, q[9]);
    }
    return fmaf(z0, fq[90], fmaf(z1, fq[91], fq[92]));
}

// Mixed-role kernel: table blocks exercise the LDS pipe, direct blocks the
// VALU/trans pipes; co-resident on each CU they fill each other's stalls.
// LDS 36KB/block caps 4 blocks/CU = 32 waves (direct blocks pay the
// allocation unused -- the cap is the same either way).
__global__ __launch_bounds__(BLK, 8) void fraud_kernel(
    const float4* __restrict__ x4, const float4* __restrict__ y4,
    const float* __restrict__ fp, const float4* __restrict__ gt4,
    float2* __restrict__ out2)
{
    __shared__ float4 tab4[TABSZ];   // 36 KB packed CR rows
    int b = blockIdx.x;
    int j = (b >> 3) & 7;            // cycles within each XCD's block stream
    int x = b & 7;                   // XCD id under round-robin dispatch
    int q = b >> 6;                  // super-group 0..31

    if (j < 6) {
        // ---------------- table role: 75% of pairs ----------------
        for (int t = threadIdx.x; t < TABSZ; t += BLK) tab4[t] = gt4[t];
        __syncthreads();

        float Wt0 = fp[0], Wt1 = fp[1], Wt2 = fp[2], Wt3 = fp[3];
        float bt0 = fp[4], bt1 = fp[5];
        float C0 = fp[6], C1 = fp[7], D0 = fp[8], D1 = fp[9];

        int rank = q * 48 + j * 8 + x;           // 0..1535 dense
        int tid = rank * BLK + threadIdx.x;      // 0..TTH-1
#pragma unroll
        for (int k = 0; k < 4; ++k) {
            int g = tid + k * TTH;               // groups [0, 4*TTH)
            float4 xa = x4[g], ya = y4[g];

            float pxa0 = fmaf(xa.x, Wt0, fmaf(xa.y, Wt1, bt0));
            float pxa1 = fmaf(xa.x, Wt2, fmaf(xa.y, Wt3, bt1));
            float pya0 = fmaf(ya.x, Wt0, fmaf(ya.y, Wt1, bt0));
            float pya1 = fmaf(ya.x, Wt2, fmaf(ya.y, Wt3, bt1));
            float dxA = xa.x - ya.x, dyA = xa.y - ya.y;
            float rA = exp2_fast(-NLOG2E * fmaf(dxA, dxA, dyA * dyA));
            float resA = rA * pair_val(tab4, pxa0, pxa1, pya0, pya1, C0, C1, D0, D1);

            float pxb0 = fmaf(xa.z, Wt0, fmaf(xa.w, Wt1, bt0));
            float pxb1 = fmaf(xa.z, Wt2, fmaf(xa.w, Wt3, bt1));
            float pyb0 = fmaf(ya.z, Wt0, fmaf(ya.w, Wt1, bt0));
            float pyb1 = fmaf(ya.z, Wt2, fmaf(ya.w, Wt3, bt1));
            float dxB = xa.z - ya.z, dyB = xa.w - ya.w;
            float rB = exp2_fast(-NLOG2E * fmaf(dxB, dxB, dyB * dyB));
            float resB = rB * pair_val(tab4, pxb0, pxb1, pyb0, pyb1, C0, C1, D0, D1);

            out2[g] = make_float2(resA, resB);
        }
    } else {
        // ---------------- direct role: 25% of pairs ----------------
        const float* fq = fp + 100;
        int rank = q * 16 + (j - 6) * 8 + x;     // 0..511 dense
        int tid = rank * BLK + threadIdx.x;      // 0..DTH-1
#pragma unroll
        for (int k = 0; k < 4; ++k) {
            int g = DBASE + tid + k * DTH;       // groups [DBASE, DBASE+4*DTH)
            float4 xa = x4[g], ya = y4[g];

            float fxA = net_eval(fq, xa.x, xa.y);
            float fyA = net_eval(fq, ya.x, ya.y);
            float dxA = xa.x - ya.x, dyA = xa.y - ya.y;
            float rA = exp2_fast(-NLOG2E * fmaf(dxA, dxA, dyA * dyA));
            float resA = rA * fxA * fyA;

            float fxB = net_eval(fq, xa.z, xa.w);
            float fyB = net_eval(fq, ya.z, ya.w);
            float dxB = xa.z - ya.z, dyB = xa.w - ya.w;
            float rB = exp2_fast(-NLOG2E * fmaf(dxB, dxB, dyB * dyB));
            float resB = rB * fxB * fyB;

            out2[g] = make_float2(resA, resB);
        }
    }
}

extern "C" void kernel_launch(void* const* d_in, const int* in_sizes, int n_in,
                              void* d_out, int out_size, void* d_ws, size_t ws_size,
                              hipStream_t stream) {
    const float* x  = (const float*)d_in[0];
    const float* y  = (const float*)d_in[1];
    const float* W0 = (const float*)d_in[2];
    const float* b0 = (const float*)d_in[3];
    const float* s0 = (const float*)d_in[4];
    const float* t0 = (const float*)d_in[5];
    const float* Ws = (const float*)d_in[6];
    const float* bs = (const float*)d_in[7];
    const float* ss = (const float*)d_in[8];
    const float* ts = (const float*)d_in[9];
    const float* Wf = (const float*)d_in[10];
    const float* bf = (const float*)d_in[11];
    float* out = (float*)d_out;
    float* fp  = (float*)d_ws;
    float4* gt4 = (float4*)(fp + 256);   // 1 KB offset, 16B-aligned

    hipLaunchKernelGGL(setup48, dim3(TAB), dim3(64), 0, stream,
                       W0, b0, s0, t0, Ws, bs, ss, ts, Wf, bf, fp, gt4);

    // n = 8,388,608 pairs -> 4,194,304 float4-groups -> 2^20 threads
    // -> 2048 blocks of 512, statically split 1536 table + 512 direct.
    dim3 block(BLK);
    dim3 grid(2048);
    hipLaunchKernelGGL(fraud_kernel, grid, block, 0, stream,
                       (const float4*)x, (const float4*)y, fp, gt4,
                       (float2*)out);
}

// Round 9
// 187.530 us; speedup vs baseline: 1.1767x; 1.1767x over previous
//
#include <hip/hip_runtime.h>
#include <math.h>

#define N_LAYERS 8
#define TAB 48
#define TABSZ (TAB * TAB)
#define LOG2E2 2.8853900817779268f   // 2*log2(e)
#define NLOG2E 1.4426950408889634f   // log2(e)
#define UCLAMP 24.0f                  // exp2 clamp: 4-product <= 2^96
#define BLK 512

typedef float f32x4 __attribute__((ext_vector_type(4)));

#if __has_builtin(__builtin_amdgcn_exp2f)
__device__ __forceinline__ float exp2_fast(float x) { return __builtin_amdgcn_exp2f(x); }
#else
__device__ __forceinline__ float exp2_fast(float x) { return __expf(0.6931471805599453f * x); }
#endif

// Register pin: forces all 8 tap vectors (32 VGPRs) to be materialized here.
// Every ds_read_b128 feeding them must be ISSUED before this point; every
// consumer sits after -> one 8-wide LDS burst + one drain, instead of the
// compiler's two serial 4-load trips (r1's 32-reg min-pressure schedule).
// Liveness-based (no sched masks, no hard cap) so unlike r2/r3 it cannot
// induce spill as long as total pressure stays near the 64-reg target.
#define PIN8(v0, v1, v2, v3, v4, v5, v6, v7)                          \
    asm volatile("" : "+v"(v0), "+v"(v1), "+v"(v2), "+v"(v3),          \
                      "+v"(v4), "+v"(v5), "+v"(v6), "+v"(v7))

// d_ws float layout:
//  [0..13]   table meta (log2-domain input layer W~,b~; C,D; lo,h)
//  [16 ..]   gt4 : packed CR rows, TABSZ float4

// setup48: one block per table row (48 blocks x 64 thr).
__global__ __launch_bounds__(64) void setup48(
    const float* __restrict__ W0, const float* __restrict__ b0,
    const float* __restrict__ s0, const float* __restrict__ t0,
    const float* __restrict__ Ws, const float* __restrict__ bs,
    const float* __restrict__ ss, const float* __restrict__ ts,
    const float* __restrict__ Wf, const float* __restrict__ bf,
    float* __restrict__ fp, float4* __restrict__ gt4) {
    __shared__ float fs[16];
    __shared__ float row[TAB];
    int iy = blockIdx.x;      // table row
    int tx = threadIdx.x;

    if (tx == 0) {
        fs[0] = LOG2E2 * W0[0]; fs[1] = LOG2E2 * W0[1];
        fs[2] = LOG2E2 * W0[2]; fs[3] = LOG2E2 * W0[3];
        fs[4] = LOG2E2 * b0[0]; fs[5] = LOG2E2 * b0[1];
        for (int c = 0; c < 2; ++c) {
            float s = s0[c], t = t0[c];
            float span = fmaxf(2.2f * s, 1e-5f);   // 10% pad each side
            float h  = span / (float)(TAB - 1);
            float lo = t - 0.5f * span;
            float ih = (float)(TAB - 1) / span;
            fs[6 + c]  = (s + 0.5f * span) * ih;   // C
            fs[8 + c]  = 2.0f * s * ih;            // D
            fs[10 + c] = lo;
            fs[12 + c] = h;
        }
        if (iy == 0)
            for (int i = 0; i < 14; ++i) fp[i] = fs[i];
    }
    __syncthreads();

    if (tx < TAB) {
        float z0 = fs[10] + (float)tx * fs[12];
        float z1 = fs[11] + (float)iy * fs[13];
        for (int l = 0; l < N_LAYERS; ++l) {
            float u0 = fmaf(z0, Ws[4 * l + 0], fmaf(z1, Ws[4 * l + 1], bs[2 * l + 0]));
            float u1 = fmaf(z0, Ws[4 * l + 2], fmaf(z1, Ws[4 * l + 3], bs[2 * l + 1]));
            z0 = fmaf(tanhf(u0), ss[2 * l + 0], ts[2 * l + 0]);
            z1 = fmaf(tanhf(u1), ss[2 * l + 1], ts[2 * l + 1]);
        }
        row[tx] = fmaf(z0, Wf[0], fmaf(z1, Wf[1], bf[0]));
    }
    __syncthreads();

    if (tx < TAB) {
        int c0 = max(tx - 1, 0);
        int c2 = min(tx + 1, TAB - 1);
        int c3 = min(tx + 2, TAB - 1);
        gt4[iy * TAB + tx] = make_float4(row[c0], row[tx], row[c2], row[c3]);
    }
}

// Catmull-Rom weights (identical expressions to r1 -> absmax unchanged).
__device__ __forceinline__ void cr_w(float f, float w[4]) {
    w[0] = f * fmaf(f, fmaf(f, -0.5f, 1.0f), -0.5f);
    w[1] = fmaf(f * f, fmaf(f, 1.5f, -2.5f), 1.0f);
    w[2] = f * fmaf(f, fmaf(f, -1.5f, 2.0f), 0.5f);
    w[3] = f * f * fmaf(f, 0.5f, -0.5f);
}

__device__ __forceinline__ float dot4(f32x4 t, const float w[4]) {
    return fmaf(t.w, w[3], fmaf(t.z, w[2], fmaf(t.y, w[1], t.x * w[0])));
}

// r1 shell: BLK=512, 36KB LDS -> 4 blocks/CU = 32 waves/CU (if VGPR<=64).
// Plain __launch_bounds__ (no min-waves arg); the PIN controls load issue.
__global__ __launch_bounds__(BLK) void fraud_kernel(
    const float4* __restrict__ x4, const float4* __restrict__ y4,
    const float* __restrict__ fp, const float4* __restrict__ gt4,
    float2* __restrict__ out2, int stride)   // 4 float4-groups (8 pairs) per thread
{
    __shared__ f32x4 tab4[TABSZ];   // 36 KB packed CR rows
    for (int j = threadIdx.x; j < TABSZ; j += BLK)
        tab4[j] = ((const f32x4*)gt4)[j];
    __syncthreads();

    float Wt0 = fp[0], Wt1 = fp[1], Wt2 = fp[2], Wt3 = fp[3];
    float bt0 = fp[4], bt1 = fp[5];
    float C0 = fp[6], C1 = fp[7], D0 = fp[8], D1 = fp[9];

    int tid = blockIdx.x * BLK + threadIdx.x;
#pragma unroll
    for (int k = 0; k < 4; ++k) {
        int g = tid + k * stride;        // coalesced float4 per lane
        float4 xa = x4[g], ya = y4[g];   // 2 pairs

        // ---- pair A coordinate chain (exact r1 math) ----
        float pxa0 = fmaf(xa.x, Wt0, fmaf(xa.y, Wt1, bt0));
        float pxa1 = fmaf(xa.x, Wt2, fmaf(xa.y, Wt3, bt1));
        float pya0 = fmaf(ya.x, Wt0, fmaf(ya.y, Wt1, bt0));
        float pya1 = fmaf(ya.x, Wt2, fmaf(ya.y, Wt3, bt1));
        float dA0 = exp2_fast(fminf(pxa0, UCLAMP)) + 1.0f;
        float dA1 = exp2_fast(fminf(pxa1, UCLAMP)) + 1.0f;
        float dA2 = exp2_fast(fminf(pya0, UCLAMP)) + 1.0f;
        float dA3 = exp2_fast(fminf(pya1, UCLAMP)) + 1.0f;
        float p2A = dA0 * dA1, p3A = p2A * dA2, p4A = p3A * dA3;
        float RA = __builtin_amdgcn_rcpf(p4A);
        float iA3 = RA * p3A;  RA *= dA3;
        float iA2 = RA * p2A;  RA *= dA2;
        float iA1 = RA * dA0;
        float iA0 = RA * dA1;
        float uxA0 = fmaf(-D0, iA0, C0), uxA1 = fmaf(-D1, iA1, C1);
        float uyA0 = fmaf(-D0, iA2, C0), uyA1 = fmaf(-D1, iA3, C1);
        int ixAx = min(max((int)uxA0, 1), TAB - 3);
        int iyAx = min(max((int)uxA1, 1), TAB - 3);
        int ixAy = min(max((int)uyA0, 1), TAB - 3);
        int iyAy = min(max((int)uyA1, 1), TAB - 3);
        float fxAx = uxA0 - (float)ixAx, fyAx = uxA1 - (float)iyAx;
        float fxAy = uyA0 - (float)ixAy, fyAy = uyA1 - (float)iyAy;
        const f32x4* pAx = tab4 + (iyAx - 1) * TAB + ixAx;
        const f32x4* pAy = tab4 + (iyAy - 1) * TAB + ixAy;

        // ---- issue pair A's 8 tap rows; pin -> one 8-wide LDS burst ----
        f32x4 ax0 = pAx[0], ax1 = pAx[TAB], ax2 = pAx[2 * TAB], ax3 = pAx[3 * TAB];
        f32x4 ay0 = pAy[0], ay1 = pAy[TAB], ay2 = pAy[2 * TAB], ay3 = pAy[3 * TAB];
        PIN8(ax0, ax1, ax2, ax3, ay0, ay1, ay2, ay3);

        // ---- pair B coords + A weights + both RBFs (covers A's latency) ----
        float pxb0 = fmaf(xa.z, Wt0, fmaf(xa.w, Wt1, bt0));
        float pxb1 = fmaf(xa.z, Wt2, fmaf(xa.w, Wt3, bt1));
        float pyb0 = fmaf(ya.z, Wt0, fmaf(ya.w, Wt1, bt0));
        float pyb1 = fmaf(ya.z, Wt2, fmaf(ya.w, Wt3, bt1));
        float dB0 = exp2_fast(fminf(pxb0, UCLAMP)) + 1.0f;
        float dB1 = exp2_fast(fminf(pxb1, UCLAMP)) + 1.0f;
        float dB2 = exp2_fast(fminf(pyb0, UCLAMP)) + 1.0f;
        float dB3 = exp2_fast(fminf(pyb1, UCLAMP)) + 1.0f;
        float p2B = dB0 * dB1, p3B = p2B * dB2, p4B = p3B * dB3;
        float RB = __builtin_amdgcn_rcpf(p4B);
        float iB3 = RB * p3B;  RB *= dB3;
        float iB2 = RB * p2B;  RB *= dB2;
        float iB1 = RB * dB0;
        float iB0 = RB * dB1;
        float uxB0 = fmaf(-D0, iB0, C0), uxB1 = fmaf(-D1, iB1, C1);
        float uyB0 = fmaf(-D0, iB2, C0), uyB1 = fmaf(-D1, iB3, C1);
        int ixBx = min(max((int)uxB0, 1), TAB - 3);
        int iyBx = min(max((int)uxB1, 1), TAB - 3);
        int ixBy = min(max((int)uyB0, 1), TAB - 3);
        int iyBy = min(max((int)uyB1, 1), TAB - 3);
        float fxBx = uxB0 - (float)ixBx, fyBx = uxB1 - (float)iyBx;
        float fxBy = uyB0 - (float)ixBy, fyBy = uyB1 - (float)iyBy;
        const f32x4* pBx = tab4 + (iyBx - 1) * TAB + ixBx;
        const f32x4* pBy = tab4 + (iyBy - 1) * TAB + ixBy;

        float wxAx[4], wyAx[4], wxAy[4], wyAy[4];
        cr_w(fxAx, wxAx); cr_w(fyAx, wyAx);
        cr_w(fxAy, wxAy); cr_w(fyAy, wyAy);

        float dxA = xa.x - ya.x, dyA = xa.y - ya.y;
        float rA = exp2_fast(-NLOG2E * fmaf(dxA, dxA, dyA * dyA));
        float dxB = xa.z - ya.z, dyB = xa.w - ya.w;
        float rB = exp2_fast(-NLOG2E * fmaf(dxB, dxB, dyB * dyB));

        // ---- consume pair A ----
        float ra0 = dot4(ax0, wxAx), ra1 = dot4(ax1, wxAx);
        float ra2 = dot4(ax2, wxAx), ra3 = dot4(ax3, wxAx);
        float gxA = fmaf(ra3, wyAx[3], fmaf(ra2, wyAx[2], fmaf(ra1, wyAx[1], ra0 * wyAx[0])));
        float sa0 = dot4(ay0, wxAy), sa1 = dot4(ay1, wxAy);
        float sa2 = dot4(ay2, wxAy), sa3 = dot4(ay3, wxAy);
        float gyA = fmaf(sa3, wyAy[3], fmaf(sa2, wyAy[2], fmaf(sa1, wyAy[1], sa0 * wyAy[0])));
        float resA = rA * (gxA * gyA);

        // ---- issue pair B's 8 tap rows; pin ----
        f32x4 bx0 = pBx[0], bx1 = pBx[TAB], bx2 = pBx[2 * TAB], bx3 = pBx[3 * TAB];
        f32x4 by0 = pBy[0], by1 = pBy[TAB], by2 = pBy[2 * TAB], by3 = pBy[3 * TAB];
        PIN8(bx0, bx1, bx2, bx3, by0, by1, by2, by3);

        // ---- B weights (covers B's latency), then consume ----
        float wxBx[4], wyBx[4], wxBy[4], wyBy[4];
        cr_w(fxBx, wxBx); cr_w(fyBx, wyBx);
        cr_w(fxBy, wxBy); cr_w(fyBy, wyBy);

        float rb0 = dot4(bx0, wxBx), rb1 = dot4(bx1, wxBx);
        float rb2 = dot4(bx2, wxBx), rb3 = dot4(bx3, wxBx);
        float gxB = fmaf(rb3, wyBx[3], fmaf(rb2, wyBx[2], fmaf(rb1, wyBx[1], rb0 * wyBx[0])));
        float sb0 = dot4(by0, wxBy), sb1 = dot4(by1, wxBy);
        float sb2 = dot4(by2, wxBy), sb3 = dot4(by3, wxBy);
        float gyB = fmaf(sb3, wyBy[3], fmaf(sb2, wyBy[2], fmaf(sb1, wyBy[1], sb0 * wyBy[0])));
        float resB = rB * (gxB * gyB);

        out2[g] = make_float2(resA, resB);
    }
}

extern "C" void kernel_launch(void* const* d_in, const int* in_sizes, int n_in,
                              void* d_out, int out_size, void* d_ws, size_t ws_size,
                              hipStream_t stream) {
    const float* x  = (const float*)d_in[0];
    const float* y  = (const float*)d_in[1];
    const float* W0 = (const float*)d_in[2];
    const float* b0 = (const float*)d_in[3];
    const float* s0 = (const float*)d_in[4];
    const float* t0 = (const float*)d_in[5];
    const float* Ws = (const float*)d_in[6];
    const float* bs = (const float*)d_in[7];
    const float* ss = (const float*)d_in[8];
    const float* ts = (const float*)d_in[9];
    const float* Wf = (const float*)d_in[10];
    const float* bf = (const float*)d_in[11];
    float* out = (float*)d_out;
    float* fp  = (float*)d_ws;
    float4* gt4 = (float4*)(fp + 16);   // 64 B offset, 16B-aligned

    hipLaunchKernelGGL(setup48, dim3(TAB), dim3(64), 0, stream,
                       W0, b0, s0, t0, Ws, bs, ss, ts, Wf, bf, fp, gt4);

    int n       = out_size;          // 8,388,608 pairs
    int ngroups = n / 2;             // float4-groups of 2 pairs
    int threads = ngroups / 4;       // 4 groups per thread = 8 pairs (2^20)
    dim3 block(BLK);
    dim3 grid(threads / BLK);        // 2^20 / 512 = 2048, exact
    hipLaunchKernelGGL(fraud_kernel, grid, block, 0, stream,
                       (const float4*)x, (const float4*)y, fp, gt4,
                       (float2*)out, threads);
}